// Round 1
// baseline (1424.065 us; speedup 1.0000x reference)
//
#include <hip/hip_runtime.h>
#include <stdint.h>

typedef unsigned short ushort_t;
typedef __attribute__((ext_vector_type(8))) short s16x8;
typedef __attribute__((ext_vector_type(4))) float f32x4;
typedef __attribute__((ext_vector_type(4))) unsigned short u16x4;

#define DEV __device__ __forceinline__

DEV ushort_t f2bf(float f) {
  union { float f; uint32_t u; } v; v.f = f;
  uint32_t r = (v.u + 0x7FFFu + ((v.u >> 16) & 1u)) >> 16;
  return (ushort_t)r;
}
DEV float bf2f(ushort_t u) {
  union { uint32_t u; float f; } v; v.u = ((uint32_t)u) << 16;
  return v.f;
}

// XOR swizzle: maps 8-way LDS bank conflict on fragment reads to free 2-way.
// Self-inverse in `chunk`, applied both at staging (source col) and frag read.
DEV int swz(int row, int chunk) { return chunk ^ (row & 3) ^ ((row >> 2) & 3); }

#define GLD_LDS16(g, l)                                     \
  __builtin_amdgcn_global_load_lds(                         \
      (const __attribute__((address_space(1))) void*)(g),   \
      (__attribute__((address_space(3))) void*)(l), 16, 0, 0)

#define MFMA16(a, b, c) __builtin_amdgcn_mfma_f32_16x16x32_bf16((a), (b), (c), 0, 0, 0)

// ---------------- fp32 -> bf16 elementwise ----------------
__global__ __launch_bounds__(256) void k_conv(const float* __restrict__ in,
                                              ushort_t* __restrict__ out, int n4) {
  int i = blockIdx.x * 256 + threadIdx.x;
  if (i >= n4) return;
  float4 v = ((const float4*)in)[i];
  u16x4 o;
  o[0] = f2bf(v.x); o[1] = f2bf(v.y); o[2] = f2bf(v.z); o[3] = f2bf(v.w);
  *((u16x4*)out + i) = o;
}

// ------------- fp32 [R][C] -> bf16 [C][R] tiled transpose -------------
__global__ __launch_bounds__(256) void k_transpose_conv(const float* __restrict__ in,
                                                        ushort_t* __restrict__ out,
                                                        int R, int C) {
  __shared__ float tile[64][65];
  int c0 = blockIdx.x * 64, r0 = blockIdx.y * 64;
  int t = threadIdx.x;
#pragma unroll
  for (int i = 0; i < 4; ++i) {
    int e = (i * 256 + t) * 4;
    int rr = e >> 6, cc = e & 63;
    float4 v = *(const float4*)(in + (size_t)(r0 + rr) * C + (c0 + cc));
    tile[rr][cc] = v.x; tile[rr][cc + 1] = v.y;
    tile[rr][cc + 2] = v.z; tile[rr][cc + 3] = v.w;
  }
  __syncthreads();
#pragma unroll
  for (int i = 0; i < 4; ++i) {
    int e = (i * 256 + t) * 4;
    int cc = e >> 6, rr = e & 63;
    u16x4 o;
    o[0] = f2bf(tile[rr][cc]);     o[1] = f2bf(tile[rr + 1][cc]);
    o[2] = f2bf(tile[rr + 2][cc]); o[3] = f2bf(tile[rr + 3][cc]);
    *(u16x4*)(out + (size_t)(c0 + cc) * R + (r0 + rr)) = o;
  }
}

// ---------------- GEMM: C[M][N] = A[M][K] * Bt[N][K]^T (bf16 in, fp32 acc) ----------------
// 128x128 tile, BK=32, 4 waves in 2x2, each wave 64x64 = 4x4 mfma tiles.
template <bool BF16OUT>
__global__ __launch_bounds__(256, 3) void k_gemm_bt(const ushort_t* __restrict__ A,
                                                    const ushort_t* __restrict__ Bt,
                                                    ushort_t* __restrict__ Cb,
                                                    float* __restrict__ Cf,
                                                    const float* __restrict__ bias,
                                                    int M, int N, int K) {
  __shared__ ushort_t lA[128 * 32];
  __shared__ ushort_t lB[128 * 32];
  int t = threadIdx.x;
  int wv = t >> 6, lane = t & 63, quad = lane >> 4, lrow = lane & 15;
  int wr = wv >> 1, wc = wv & 1;
  int n0 = blockIdx.x * 128, m0 = blockIdx.y * 128;

  f32x4 acc[4][4];
#pragma unroll
  for (int i = 0; i < 4; ++i)
#pragma unroll
    for (int j = 0; j < 4; ++j) acc[i][j] = (f32x4){0.f, 0.f, 0.f, 0.f};

  for (int k0 = 0; k0 < K; k0 += 32) {
    __syncthreads();
#pragma unroll
    for (int c = 0; c < 2; ++c) {
      int se = (c * 256 + t) * 8;       // linear bf16 slot this lane stages
      int row = se >> 5;                // tile row (32 elems per row)
      int scn = (se >> 3) & 3;          // LDS chunk slot
      int col = swz(row, scn) * 8;      // swizzled source column
      GLD_LDS16(A + (size_t)(m0 + row) * K + k0 + col, lA + (c * 256 + wv * 64) * 8);
      GLD_LDS16(Bt + (size_t)(n0 + row) * K + k0 + col, lB + (c * 256 + wv * 64) * 8);
    }
    __syncthreads();
    s16x8 af[4], bfr[4];
#pragma unroll
    for (int i = 0; i < 4; ++i) {
      int row = wr * 64 + i * 16 + lrow;
      af[i] = *(const s16x8*)(lA + row * 32 + swz(row, quad) * 8);
    }
#pragma unroll
    for (int j = 0; j < 4; ++j) {
      int row = wc * 64 + j * 16 + lrow;
      bfr[j] = *(const s16x8*)(lB + row * 32 + swz(row, quad) * 8);
    }
#pragma unroll
    for (int i = 0; i < 4; ++i)
#pragma unroll
      for (int j = 0; j < 4; ++j) acc[i][j] = MFMA16(af[i], bfr[j], acc[i][j]);
  }

#pragma unroll
  for (int i = 0; i < 4; ++i)
#pragma unroll
    for (int j = 0; j < 4; ++j)
#pragma unroll
      for (int r = 0; r < 4; ++r) {
        int gr = m0 + wr * 64 + i * 16 + quad * 4 + r;
        int gc = n0 + wc * 64 + j * 16 + lrow;
        if (BF16OUT)
          Cb[(size_t)gr * N + gc] = f2bf(acc[i][j][r]);
        else
          Cf[(size_t)gr * N + gc] = acc[i][j][r] + bias[gc];
      }
}

// ---------------- RoPE in-place on q,k sections of qkv (bf16) ----------------
__global__ __launch_bounds__(256) void k_rope(ushort_t* __restrict__ qkv) {
  int tid = blockIdx.x * 256 + threadIdx.x;  // B*S*H*64 = 8388608
  int p = tid & 63;
  int h = (tid >> 6) & 31;
  int s = (tid >> 11) & 2047;
  int b = tid >> 22;
  size_t base = (size_t)(b * 2048 + s) * 12288 + h * 128 + 2 * p;
  float inv_freq = __expf(-(float)p * 0.14391156509165667f);  // ln(1e4)/64
  float ang = (float)s * inv_freq;
  float c = cosf(ang), sn = sinf(ang);
  float q0 = bf2f(qkv[base]), q1 = bf2f(qkv[base + 1]);
  qkv[base]        = f2bf(q0 * c - q1 * sn);
  qkv[base + 1]    = f2bf(q0 * sn + q1 * c);
  float k0 = bf2f(qkv[base + 4096]), k1 = bf2f(qkv[base + 4097]);
  qkv[base + 4096] = f2bf(k0 * c - k1 * sn);
  qkv[base + 4097] = f2bf(k0 * sn + k1 * c);
}

// ---------------- build V^T: vt[b,h,d,s] from qkv v-section ----------------
__global__ __launch_bounds__(256) void k_build_vt(const ushort_t* __restrict__ qkv,
                                                  ushort_t* __restrict__ vt) {
  const int S = 2048;
  int s0 = blockIdx.x * 64;
  int bh = blockIdx.y;
  int b = bh >> 5, h = bh & 31;
  __shared__ ushort_t tl[64][136];
  int t = threadIdx.x;
  const ushort_t* src = qkv + (size_t)(b * S + s0) * 12288 + 8192 + h * 128;
#pragma unroll
  for (int i = 0; i < 4; ++i) {
    int e = (i * 256 + t) * 8;
    int row = e >> 7, col = e & 127;
    *(s16x8*)&tl[row][col] = *(const s16x8*)(src + (size_t)row * 12288 + col);
  }
  __syncthreads();
  ushort_t* dst = vt + (size_t)bh * 128 * S;
#pragma unroll
  for (int i = 0; i < 4; ++i) {
    int e = (i * 256 + t) * 8;
    int d = e >> 6, ss = e & 63;
    s16x8 o;
#pragma unroll
    for (int j = 0; j < 8; ++j) o[j] = (short)tl[ss + j][d];
    *(s16x8*)(dst + (size_t)d * S + s0 + ss) = o;
  }
}

// ---------------- causal flash attention ----------------
// grid: (S/64, B*H). block 256 = 4 waves; wave w owns q rows [q0+16w, q0+16w+16).
__global__ __launch_bounds__(256, 2) void k_attn(const ushort_t* __restrict__ qkv,
                                                 const ushort_t* __restrict__ vt,
                                                 ushort_t* __restrict__ ctx) {
  const int S = 2048;
  int qt = blockIdx.x, bh = blockIdx.y;
  int b = bh >> 5, h = bh & 31;
  int q0 = qt * 64;
  int t = threadIdx.x;
  int wv = t >> 6, lane = t & 63, quad = lane >> 4, lrow = lane & 15;

  __shared__ ushort_t lQ[64][136];
  __shared__ ushort_t lK[64][136];
  __shared__ ushort_t lV[128][72];     // V^T tile: [d][kv]
  __shared__ ushort_t lP[4][16][72];   // per-wave P round-trip (C-layout -> A-layout)

  const ushort_t* qp = qkv + (size_t)(b * S) * 12288 + h * 128;
  const ushort_t* kp = qp + 4096;
  const ushort_t* vp = vt + (size_t)bh * 128 * S;

#pragma unroll
  for (int i = 0; i < 4; ++i) {
    int e = (i * 256 + t) * 8;
    int row = e >> 7, col = e & 127;
    *(s16x8*)&lQ[row][col] = *(const s16x8*)(qp + (size_t)(q0 + row) * 12288 + col);
  }

  f32x4 O[8];
#pragma unroll
  for (int i = 0; i < 8; ++i) O[i] = (f32x4){0.f, 0.f, 0.f, 0.f};
  float m_i[4], l_i[4];
#pragma unroll
  for (int r = 0; r < 4; ++r) { m_i[r] = -__builtin_inff(); l_i[r] = 0.f; }

  const float scale = 0.08838834764831845f;  // 1/sqrt(128)

  for (int kvt = 0; kvt <= qt; ++kvt) {
    int kv0 = kvt * 64;
    __syncthreads();  // prior iter's PV reads of lV/lP done before restage
#pragma unroll
    for (int i = 0; i < 4; ++i) {
      int e = (i * 256 + t) * 8;
      int row = e >> 7, col = e & 127;
      *(s16x8*)&lK[row][col] = *(const s16x8*)(kp + (size_t)(kv0 + row) * 12288 + col);
    }
#pragma unroll
    for (int i = 0; i < 4; ++i) {
      int e = (i * 256 + t) * 8;
      int d = e >> 6, c = e & 63;
      *(s16x8*)&lV[d][c] = *(const s16x8*)(vp + (size_t)d * S + kv0 + c);
    }
    __syncthreads();

    // S_tile = Q_tile @ K_tile^T
    f32x4 sc[4];
#pragma unroll
    for (int nt = 0; nt < 4; ++nt) sc[nt] = (f32x4){0.f, 0.f, 0.f, 0.f};
#pragma unroll
    for (int ks = 0; ks < 4; ++ks) {
      s16x8 a = *(const s16x8*)&lQ[wv * 16 + lrow][ks * 32 + quad * 8];
#pragma unroll
      for (int nt = 0; nt < 4; ++nt) {
        s16x8 bb = *(const s16x8*)&lK[nt * 16 + lrow][ks * 32 + quad * 8];
        sc[nt] = MFMA16(a, bb, sc[nt]);
      }
    }

    // mask + online softmax (C layout: row = quad*4+r, col = lrow)
    int qr = q0 + wv * 16 + quad * 4;
    float mt[4];
#pragma unroll
    for (int r = 0; r < 4; ++r) mt[r] = -__builtin_inff();
    float pvl[4][4];
#pragma unroll
    for (int nt = 0; nt < 4; ++nt) {
      int kc = kv0 + nt * 16 + lrow;
#pragma unroll
      for (int r = 0; r < 4; ++r) {
        float sv = sc[nt][r] * scale;
        if (kc > qr + r) sv = -__builtin_inff();
        pvl[nt][r] = sv;
        mt[r] = fmaxf(mt[r], sv);
      }
    }
#pragma unroll
    for (int r = 0; r < 4; ++r)
#pragma unroll
      for (int off = 1; off < 16; off <<= 1)
        mt[r] = fmaxf(mt[r], __shfl_xor(mt[r], off, 16));

    float al[4], ls[4];
#pragma unroll
    for (int r = 0; r < 4; ++r) {
      float mn = fmaxf(m_i[r], mt[r]);
      al[r] = __expf(m_i[r] - mn);
      m_i[r] = mn;
      ls[r] = 0.f;
    }
#pragma unroll
    for (int nt = 0; nt < 4; ++nt)
#pragma unroll
      for (int r = 0; r < 4; ++r) {
        float p = __expf(pvl[nt][r] - m_i[r]);
        ushort_t pu = f2bf(p);
        lP[wv][quad * 4 + r][nt * 16 + lrow] = pu;
        ls[r] += bf2f(pu);  // denominator from the same rounded P the PV mfma sees
      }
#pragma unroll
    for (int r = 0; r < 4; ++r) {
#pragma unroll
      for (int off = 1; off < 16; off <<= 1) ls[r] += __shfl_xor(ls[r], off, 16);
      l_i[r] = al[r] * l_i[r] + ls[r];
    }
#pragma unroll
    for (int f = 0; f < 8; ++f)
#pragma unroll
      for (int r = 0; r < 4; ++r) O[f][r] *= al[r];
    __syncthreads();  // P visible (written in C-layout, read in A-layout)

    // O += P @ V
#pragma unroll
    for (int ks = 0; ks < 2; ++ks) {
      s16x8 a = *(const s16x8*)&lP[wv][lrow][ks * 32 + quad * 8];
#pragma unroll
      for (int f = 0; f < 8; ++f) {
        s16x8 bb = *(const s16x8*)&lV[f * 16 + lrow][ks * 32 + quad * 8];
        O[f] = MFMA16(a, bb, O[f]);
      }
    }
  }

#pragma unroll
  for (int r = 0; r < 4; ++r) l_i[r] = 1.f / l_i[r];
#pragma unroll
  for (int f = 0; f < 8; ++f)
#pragma unroll
    for (int r = 0; r < 4; ++r) {
      size_t idx = (size_t)(b * S + q0 + wv * 16 + quad * 4 + r) * 4096 + h * 128 + f * 16 + lrow;
      ctx[idx] = f2bf(O[f][r] * l_i[r]);
    }
}

// ---------------- launcher ----------------
extern "C" void kernel_launch(void* const* d_in, const int* in_sizes, int n_in,
                              void* d_out, int out_size, void* d_ws, size_t ws_size,
                              hipStream_t stream) {
  const float* x      = (const float*)d_in[0];  // [2,2048,4096]
  const float* w_qkv  = (const float*)d_in[1];  // [4096,12288]
  const float* w_proj = (const float*)d_in[2];  // [4096,4096]
  const float* b_proj = (const float*)d_in[3];  // [4096]
  float* out = (float*)d_out;

  char* ws = (char*)d_ws;
  ushort_t* xb     = (ushort_t*)(ws);                 // 33,554,432 B
  ushort_t* wqkvt  = (ushort_t*)(ws + 33554432ULL);   // 100,663,296 B  [12288][4096]
  ushort_t* wprojt = (ushort_t*)(ws + 134217728ULL);  // 33,554,432 B   [4096][4096]
  ushort_t* qkvb   = (ushort_t*)(ws + 167772160ULL);  // 100,663,296 B  [4096][12288]
  ushort_t* vt     = (ushort_t*)(ws + 268435456ULL);  // 33,554,432 B   [64][128][2048]
  ushort_t* ctx    = (ushort_t*)(ws + 301989888ULL);  // 33,554,432 B   [4096][4096]

  k_conv<<<16384, 256, 0, stream>>>(x, xb, 16777216 / 4);
  k_transpose_conv<<<dim3(192, 64), 256, 0, stream>>>(w_qkv, wqkvt, 4096, 12288);
  k_transpose_conv<<<dim3(64, 64), 256, 0, stream>>>(w_proj, wprojt, 4096, 4096);
  k_gemm_bt<true><<<dim3(96, 32), 256, 0, stream>>>(xb, wqkvt, qkvb, nullptr, nullptr,
                                                    4096, 12288, 4096);
  k_rope<<<32768, 256, 0, stream>>>(qkvb);
  k_build_vt<<<dim3(32, 64), 256, 0, stream>>>(qkvb, vt);
  k_attn<<<dim3(32, 64), 256, 0, stream>>>(qkvb, vt, ctx);
  k_gemm_bt<false><<<dim3(32, 32), 256, 0, stream>>>(ctx, wprojt, nullptr, out, b_proj,
                                                     4096, 4096, 4096);
}

// Round 4
// 1383.027 us; speedup vs baseline: 1.0297x; 1.0297x over previous
//
#include <hip/hip_runtime.h>
#include <stdint.h>

typedef unsigned short ushort_t;
typedef __attribute__((ext_vector_type(8))) short s16x8;
typedef __attribute__((ext_vector_type(4))) float f32x4;
typedef __attribute__((ext_vector_type(4))) unsigned short u16x4;

#define DEV __device__ __forceinline__

DEV ushort_t f2bf(float f) {
  union { float f; uint32_t u; } v; v.f = f;
  uint32_t r = (v.u + 0x7FFFu + ((v.u >> 16) & 1u)) >> 16;
  return (ushort_t)r;
}
DEV float bf2f(ushort_t u) {
  union { uint32_t u; float f; } v; v.u = ((uint32_t)u) << 16;
  return v.f;
}

// XOR swizzle (GEMM tiles): maps fragment-read bank aliasing to the minimal 2-sweep.
DEV int swz(int row, int chunk) { return chunk ^ (row & 3) ^ ((row >> 2) & 3); }

#define GLD_LDS16(g, l)                                     \
  __builtin_amdgcn_global_load_lds(                         \
      (const __attribute__((address_space(1))) void*)(g),   \
      (__attribute__((address_space(3))) void*)(l), 16, 0, 0)

#define MFMA16(a, b, c) __builtin_amdgcn_mfma_f32_16x16x32_bf16((a), (b), (c), 0, 0, 0)

// ---------------- fp32 -> bf16 elementwise ----------------
__global__ __launch_bounds__(256) void k_conv(const float* __restrict__ in,
                                              ushort_t* __restrict__ out, int n4) {
  int i = blockIdx.x * 256 + threadIdx.x;
  if (i >= n4) return;
  float4 v = ((const float4*)in)[i];
  u16x4 o;
  o[0] = f2bf(v.x); o[1] = f2bf(v.y); o[2] = f2bf(v.z); o[3] = f2bf(v.w);
  *((u16x4*)out + i) = o;
}

// ------------- fp32 [R][C] -> bf16 [C][R] tiled transpose -------------
__global__ __launch_bounds__(256) void k_transpose_conv(const float* __restrict__ in,
                                                        ushort_t* __restrict__ out,
                                                        int R, int C) {
  __shared__ float tile[64][65];
  int c0 = blockIdx.x * 64, r0 = blockIdx.y * 64;
  int t = threadIdx.x;
#pragma unroll
  for (int i = 0; i < 4; ++i) {
    int e = (i * 256 + t) * 4;
    int rr = e >> 6, cc = e & 63;
    float4 v = *(const float4*)(in + (size_t)(r0 + rr) * C + (c0 + cc));
    tile[rr][cc] = v.x; tile[rr][cc + 1] = v.y;
    tile[rr][cc + 2] = v.z; tile[rr][cc + 3] = v.w;
  }
  __syncthreads();
#pragma unroll
  for (int i = 0; i < 4; ++i) {
    int e = (i * 256 + t) * 4;
    int cc = e >> 6, rr = e & 63;
    u16x4 o;
    o[0] = f2bf(tile[rr][cc]);     o[1] = f2bf(tile[rr + 1][cc]);
    o[2] = f2bf(tile[rr + 2][cc]); o[3] = f2bf(tile[rr + 3][cc]);
    *(u16x4*)(out + (size_t)(c0 + cc) * R + (r0 + rr)) = o;
  }
}

// ---------------- GEMM: C[M][N] = A[M][K] * Bt[N][K]^T (bf16 in, fp32 acc) ----------------
// 128x128 tile, BK=32, 4 waves in 2x2, each wave 64x64 = 4x4 mfma tiles.
// ROPE: fused interleaved rotary on epilogue fp32 acc for cols < 8192 (q,k sections).
template <bool BF16OUT, bool ROPE>
__global__ __launch_bounds__(256, 3) void k_gemm_bt(const ushort_t* __restrict__ A,
                                                    const ushort_t* __restrict__ Bt,
                                                    ushort_t* __restrict__ Cb,
                                                    float* __restrict__ Cf,
                                                    const float* __restrict__ bias,
                                                    int M, int N, int K) {
  __shared__ ushort_t lA[128 * 32];
  __shared__ ushort_t lB[128 * 32];
  int t = threadIdx.x;
  int wv = t >> 6, lane = t & 63, quad = lane >> 4, lrow = lane & 15;
  int wr = wv >> 1, wc = wv & 1;
  int n0 = blockIdx.x * 128, m0 = blockIdx.y * 128;

  f32x4 acc[4][4];
#pragma unroll
  for (int i = 0; i < 4; ++i)
#pragma unroll
    for (int j = 0; j < 4; ++j) acc[i][j] = (f32x4){0.f, 0.f, 0.f, 0.f};

  for (int k0 = 0; k0 < K; k0 += 32) {
    __syncthreads();
#pragma unroll
    for (int c = 0; c < 2; ++c) {
      int se = (c * 256 + t) * 8;       // linear bf16 slot this lane stages
      int row = se >> 5;                // tile row (32 elems per row)
      int scn = (se >> 3) & 3;          // LDS chunk slot
      int col = swz(row, scn) * 8;      // swizzled source column
      GLD_LDS16(A + (size_t)(m0 + row) * K + k0 + col, lA + (c * 256 + wv * 64) * 8);
      GLD_LDS16(Bt + (size_t)(n0 + row) * K + k0 + col, lB + (c * 256 + wv * 64) * 8);
    }
    __syncthreads();
    s16x8 af[4], bfr[4];
#pragma unroll
    for (int i = 0; i < 4; ++i) {
      int row = wr * 64 + i * 16 + lrow;
      af[i] = *(const s16x8*)(lA + row * 32 + swz(row, quad) * 8);
    }
#pragma unroll
    for (int j = 0; j < 4; ++j) {
      int row = wc * 64 + j * 16 + lrow;
      bfr[j] = *(const s16x8*)(lB + row * 32 + swz(row, quad) * 8);
    }
#pragma unroll
    for (int i = 0; i < 4; ++i)
#pragma unroll
      for (int j = 0; j < 4; ++j) acc[i][j] = MFMA16(af[i], bfr[j], acc[i][j]);
  }

  bool do_rope = ROPE && (n0 < 8192);   // block-uniform
  float sgn_sel = (lrow & 1) ? 1.f : -1.f;
#pragma unroll
  for (int j = 0; j < 4; ++j) {
    int gc = n0 + wc * 64 + j * 16 + lrow;
    float freq = 0.f;
    if (do_rope) {
      int p = (gc & 127) >> 1;
      freq = __expf(-(float)p * 0.14391156509165667f);  // ln(1e4)/64
    }
#pragma unroll
    for (int i = 0; i < 4; ++i)
#pragma unroll
      for (int r = 0; r < 4; ++r) {
        int gr = m0 + wr * 64 + i * 16 + quad * 4 + r;
        float val = acc[i][j][r];
        if (do_rope) {
          float other = __shfl_xor(val, 1);
          float sv, cv;
          sincosf((float)(gr & 2047) * freq, &sv, &cv);
          val = fmaf(other, sgn_sel * sv, val * cv);
        }
        if (BF16OUT)
          Cb[(size_t)gr * N + gc] = f2bf(val);
        else
          Cf[(size_t)gr * N + gc] = val + bias[gc];
      }
  }
}

// ---------------- build V^T: vt[b,h,d,s] from qkv v-section ----------------
__global__ __launch_bounds__(256) void k_build_vt(const ushort_t* __restrict__ qkv,
                                                  ushort_t* __restrict__ vt) {
  const int S = 2048;
  int s0 = blockIdx.x * 64;
  int bh = blockIdx.y;
  int b = bh >> 5, h = bh & 31;
  __shared__ ushort_t tl[64][136];
  int t = threadIdx.x;
  const ushort_t* src = qkv + (size_t)(b * S + s0) * 12288 + 8192 + h * 128;
#pragma unroll
  for (int i = 0; i < 4; ++i) {
    int e = (i * 256 + t) * 8;
    int row = e >> 7, col = e & 127;
    *(s16x8*)&tl[row][col] = *(const s16x8*)(src + (size_t)row * 12288 + col);
  }
  __syncthreads();
  ushort_t* dst = vt + (size_t)bh * 128 * S;
#pragma unroll
  for (int i = 0; i < 4; ++i) {
    int e = (i * 256 + t) * 8;
    int d = e >> 6, ss = e & 63;
    s16x8 o;
#pragma unroll
    for (int j = 0; j < 8; ++j) o[j] = (short)tl[ss + j][d];
    *(s16x8*)(dst + (size_t)d * S + s0 + ss) = o;
  }
}

// ---------------- causal flash attention ----------------
// grid: (S/128, B*H). block 256 = 4 waves; wave wv owns q rows [q0+32wv, +32).
// Q in registers; K/V staged via global_load_lds w/ XOR swizzle; 2 barriers/iter.
__global__ __launch_bounds__(256, 2) void k_attn(const ushort_t* __restrict__ qkv,
                                                 const ushort_t* __restrict__ vt,
                                                 ushort_t* __restrict__ ctx) {
  const int S = 2048;
  int qt = blockIdx.x, bh = blockIdx.y;
  int b = bh >> 5, h = bh & 31;
  int q0 = qt * 128;
  int t = threadIdx.x;
  int wv = t >> 6, lane = t & 63, quad = lane >> 4, lrow = lane & 15;

  __shared__ ushort_t lK[64 * 128];   // [kv][d], swizzled 16B chunks
  __shared__ ushort_t lV[128 * 64];   // [d][kv], swizzled 16B chunks
  __shared__ ushort_t lP[4][32][72];  // per-wave P round-trip (C-layout -> A-layout)

  const ushort_t* qp = qkv + (size_t)(b * S) * 12288 + h * 128;
  const ushort_t* kp = qp + 4096;
  const ushort_t* vp = vt + (size_t)bh * 128 * S;

  // Q fragments in registers (rope already applied by fused GEMM epilogue)
  s16x8 qf[2][4];
  int qrb = q0 + wv * 32;
#pragma unroll
  for (int ti = 0; ti < 2; ++ti)
#pragma unroll
    for (int ks = 0; ks < 4; ++ks)
      qf[ti][ks] = *(const s16x8*)(qp + (size_t)(qrb + ti * 16 + lrow) * 12288 +
                                   ks * 32 + quad * 8);

  f32x4 O[2][8];
#pragma unroll
  for (int ti = 0; ti < 2; ++ti)
#pragma unroll
    for (int f = 0; f < 8; ++f) O[ti][f] = (f32x4){0.f, 0.f, 0.f, 0.f};
  float m_i[2][4], l_i[2][4];
#pragma unroll
  for (int ti = 0; ti < 2; ++ti)
#pragma unroll
    for (int r = 0; r < 4; ++r) { m_i[ti][r] = -__builtin_inff(); l_i[ti][r] = 0.f; }

  const float scale = 0.08838834764831845f;  // 1/sqrt(128)
  int qhi = q0 + 127;

  for (int kv0 = 0; kv0 <= qhi; kv0 += 64) {
    __syncthreads();  // prior iter's lK/lV reads done before restage
    {
      int ck = lane & 15;
      int cv = lane & 7;
#pragma unroll
      for (int it = 0; it < 4; ++it) {
        int slot = wv * 4 + it;
        // K: 1024B = 4 rows of 256B; lane -> row slot*4+(lane>>4), chunk lane&15
        int rowk = slot * 4 + (lane >> 4);
        int cpk = (ck & 8) | ((ck & 7) ^ (rowk & 7));
        GLD_LDS16(kp + (size_t)(kv0 + rowk) * 12288 + cpk * 8, lK + slot * 512);
        // V^T: 1024B = 8 rows of 128B; lane -> row slot*8+(lane>>3), chunk lane&7
        int rowv = slot * 8 + (lane >> 3);
        int cpv = cv ^ (rowv & 7);
        GLD_LDS16(vp + (size_t)rowv * S + kv0 + cpv * 8, lV + slot * 512);
      }
    }
    __syncthreads();

    // S_tile = Q_tile @ K_tile^T
    f32x4 sc[2][4];
#pragma unroll
    for (int ti = 0; ti < 2; ++ti)
#pragma unroll
      for (int nt = 0; nt < 4; ++nt) sc[ti][nt] = (f32x4){0.f, 0.f, 0.f, 0.f};
#pragma unroll
    for (int ks = 0; ks < 4; ++ks) {
      s16x8 bk[4];
#pragma unroll
      for (int nt = 0; nt < 4; ++nt) {
        int row = nt * 16 + lrow;
        int cc = ks * 4 + quad;
        int cp = (cc & 8) | ((cc & 7) ^ (row & 7));
        bk[nt] = *(const s16x8*)(lK + row * 128 + cp * 8);
      }
#pragma unroll
      for (int ti = 0; ti < 2; ++ti)
#pragma unroll
        for (int nt = 0; nt < 4; ++nt) sc[ti][nt] = MFMA16(qf[ti][ks], bk[nt], sc[ti][nt]);
    }

    // online softmax per 16-row tile (C layout: row = quad*4+r, col = lrow)
#pragma unroll
    for (int ti = 0; ti < 2; ++ti) {
      int qr = qrb + ti * 16 + quad * 4;
      float mt[4];
#pragma unroll
      for (int r = 0; r < 4; ++r) mt[r] = -__builtin_inff();
      float pvl[4][4];
#pragma unroll
      for (int nt = 0; nt < 4; ++nt) {
        int kc = kv0 + nt * 16 + lrow;
#pragma unroll
        for (int r = 0; r < 4; ++r) {
          float sv = sc[ti][nt][r] * scale;
          if (kc > qr + r) sv = -__builtin_inff();
          pvl[nt][r] = sv;
          mt[r] = fmaxf(mt[r], sv);
        }
      }
#pragma unroll
      for (int r = 0; r < 4; ++r)
#pragma unroll
        for (int off = 1; off < 16; off <<= 1)
          mt[r] = fmaxf(mt[r], __shfl_xor(mt[r], off, 16));

      float al[4], ls[4];
#pragma unroll
      for (int r = 0; r < 4; ++r) {
        float mn = fmaxf(m_i[ti][r], mt[r]);
        al[r] = __expf(m_i[ti][r] - mn);
        m_i[ti][r] = mn;
        ls[r] = 0.f;
      }
#pragma unroll
      for (int nt = 0; nt < 4; ++nt)
#pragma unroll
        for (int r = 0; r < 4; ++r) {
          float p = __expf(pvl[nt][r] - m_i[ti][r]);
          ushort_t pu = f2bf(p);
          lP[wv][ti * 16 + quad * 4 + r][nt * 16 + lrow] = pu;
          ls[r] += bf2f(pu);  // denominator from the same rounded P the PV mfma sees
        }
#pragma unroll
      for (int r = 0; r < 4; ++r) {
#pragma unroll
        for (int off = 1; off < 16; off <<= 1) ls[r] += __shfl_xor(ls[r], off, 16);
        l_i[ti][r] = al[r] * l_i[ti][r] + ls[r];
      }
#pragma unroll
      for (int f = 0; f < 8; ++f)
#pragma unroll
        for (int r = 0; r < 4; ++r) O[ti][f][r] *= al[r];
    }
    // NOTE: no barrier here — lP[wv] is same-wave write->read; lgkmcnt covers it.

    // O += P @ V
#pragma unroll
    for (int ks = 0; ks < 2; ++ks) {
      s16x8 pa[2];
#pragma unroll
      for (int ti = 0; ti < 2; ++ti)
        pa[ti] = *(const s16x8*)&lP[wv][ti * 16 + lrow][ks * 32 + quad * 8];
#pragma unroll
      for (int f = 0; f < 8; ++f) {
        int row = f * 16 + lrow;
        int cc = ks * 4 + quad;
        int cp = cc ^ (row & 7);
        s16x8 bv = *(const s16x8*)(lV + row * 64 + cp * 8);
#pragma unroll
        for (int ti = 0; ti < 2; ++ti) O[ti][f] = MFMA16(pa[ti], bv, O[ti][f]);
      }
    }
  }

#pragma unroll
  for (int ti = 0; ti < 2; ++ti) {
    float inv[4];
#pragma unroll
    for (int r = 0; r < 4; ++r) inv[r] = 1.f / l_i[ti][r];
#pragma unroll
    for (int f = 0; f < 8; ++f)
#pragma unroll
      for (int r = 0; r < 4; ++r) {
        size_t idx = (size_t)(b * S + qrb + ti * 16 + quad * 4 + r) * 4096 +
                     h * 128 + f * 16 + lrow;
        ctx[idx] = f2bf(O[ti][f][r] * inv[r]);
      }
  }
}

// ---------------- launcher ----------------
extern "C" void kernel_launch(void* const* d_in, const int* in_sizes, int n_in,
                              void* d_out, int out_size, void* d_ws, size_t ws_size,
                              hipStream_t stream) {
  const float* x      = (const float*)d_in[0];  // [2,2048,4096]
  const float* w_qkv  = (const float*)d_in[1];  // [4096,12288]
  const float* w_proj = (const float*)d_in[2];  // [4096,4096]
  const float* b_proj = (const float*)d_in[3];  // [4096]
  float* out = (float*)d_out;

  char* ws = (char*)d_ws;
  ushort_t* xb     = (ushort_t*)(ws);                 // 33,554,432 B
  ushort_t* wqkvt  = (ushort_t*)(ws + 33554432ULL);   // 100,663,296 B  [12288][4096]
  ushort_t* wprojt = (ushort_t*)(ws + 134217728ULL);  // 33,554,432 B   [4096][4096]
  ushort_t* qkvb   = (ushort_t*)(ws + 167772160ULL);  // 100,663,296 B  [4096][12288]
  ushort_t* vt     = (ushort_t*)(ws + 268435456ULL);  // 33,554,432 B   [64][128][2048]
  ushort_t* ctx    = (ushort_t*)(ws + 301989888ULL);  // 33,554,432 B   [4096][4096]

  k_conv<<<16384, 256, 0, stream>>>(x, xb, 16777216 / 4);
  k_transpose_conv<<<dim3(192, 64), 256, 0, stream>>>(w_qkv, wqkvt, 4096, 12288);
  k_transpose_conv<<<dim3(64, 64), 256, 0, stream>>>(w_proj, wprojt, 4096, 4096);
  k_gemm_bt<true, true><<<dim3(96, 32), 256, 0, stream>>>(xb, wqkvt, qkvb, nullptr,
                                                          nullptr, 4096, 12288, 4096);
  k_build_vt<<<dim3(32, 64), 256, 0, stream>>>(qkvb, vt);
  k_attn<<<dim3(16, 64), 256, 0, stream>>>(qkvb, vt, ctx);
  k_gemm_bt<false, false><<<dim3(32, 32), 256, 0, stream>>>(ctx, wprojt, nullptr, out,
                                                            b_proj, 4096, 4096, 4096);
}